// Round 10
// baseline (474.996 us; speedup 1.0000x reference)
//
#include <hip/hip_runtime.h>
#include <hip/hip_bf16.h>

#define NNODES 131072
#define LGRAPH 256
#define BGRAPH 512
#define DIN 300
#define DH 96
#define EPG 2048
#define VOCAB 50001
#define NCLS 20
#define NEG 0.2f
#define EMB_ROWS 50048   // VOCAB padded to 128-row tiles
#define EMB_K 320        // 300 padded to 32-multiple
#define WS 100           // padded LDS stride (halfs), conflict-free for b128
#define XS 104           // padded LDS stride (halfs) for x/h tiles

typedef __attribute__((ext_vector_type(4))) float f32x4;
typedef __attribute__((ext_vector_type(8))) short bf16x8;
typedef __attribute__((ext_vector_type(8))) unsigned short u16x8;
#define MFMA16(a, b, c) __builtin_amdgcn_mfma_f32_16x16x32_bf16(a, b, c, 0, 0, 0)

__device__ __forceinline__ unsigned short f2b(float f) {
  __hip_bfloat16 h = __float2bfloat16(f);
  return *reinterpret_cast<unsigned short*>(&h);
}
__device__ __forceinline__ float b2f(unsigned short u) {
  unsigned v = ((unsigned)u) << 16;
  return __uint_as_float(v);
}
__device__ __forceinline__ float sigm(float v) { return 1.f / (1.f + __expf(-v)); }
__device__ __forceinline__ float ftanh(float x) {
  float ax = fabsf(x);
  float e = __expf(ax + ax);
  float t = 1.f - 2.f / (e + 1.f);
  return copysignf(t, x);
}

// ---- weight prep: W[k][c] f32 -> WT[c][k] bf16 ; WeT ; combined biases ----
__global__ void k_prep_w(const float* __restrict__ Wg, const float* __restrict__ Wz0,
                         const float* __restrict__ Wz1, const float* __restrict__ Wr0,
                         const float* __restrict__ Wr1, const float* __restrict__ Wh0,
                         const float* __restrict__ Wh1, const float* __restrict__ Wemb,
                         const float* __restrict__ We,
                         const float* __restrict__ bz0, const float* __restrict__ bz1,
                         const float* __restrict__ br0, const float* __restrict__ br1,
                         const float* __restrict__ bh0, const float* __restrict__ bh1,
                         unsigned short* __restrict__ WT, unsigned short* __restrict__ WeT,
                         float* __restrict__ bc) {
  const int b = blockIdx.x, t = threadIdx.x;
  if (b < 8) {
    const float* src = (b == 0) ? Wg : (b == 1) ? Wz0 : (b == 2) ? Wz1 : (b == 3) ? Wr0
                     : (b == 4) ? Wr1 : (b == 5) ? Wh0 : (b == 6) ? Wh1 : Wemb;
    unsigned short* dst = WT + b * DH * DH;
    for (int i = t; i < DH * DH; i += 256) {
      int c = i / DH, k = i - c * DH;
      dst[i] = f2b(src[k * DH + c]);
    }
  } else if (b == 8) {
    for (int i = t; i < DH * EMB_K; i += 256) {
      int c = i / EMB_K, k = i - c * EMB_K;
      WeT[i] = (k < DIN) ? f2b(We[k * DH + c]) : (unsigned short)0;
    }
  } else {
    if (t < DH) {
      bc[t] = bz0[t] + bz1[t];
      bc[DH + t] = br0[t] + br1[t];
      bc[2 * DH + t] = bh0[t] + bh1[t];
    }
  }
}

// ---- Tb = embed @ We  (MFMA, M-tile 128, f32 A converted in-reg, bf16 out) ----
__device__ __forceinline__ bf16x8 ldcvt(const float* __restrict__ p, int row, int ko) {
  bf16x8 r;
  if (row < VOCAB) {
    float4 c0 = (ko + 4 <= DIN) ? *(const float4*)&p[row * DIN + ko]
                                : make_float4(0.f, 0.f, 0.f, 0.f);
    float4 c1 = (ko + 8 <= DIN) ? *(const float4*)&p[row * DIN + ko + 4]
                                : make_float4(0.f, 0.f, 0.f, 0.f);
    r[0] = (short)f2b(c0.x); r[1] = (short)f2b(c0.y);
    r[2] = (short)f2b(c0.z); r[3] = (short)f2b(c0.w);
    r[4] = (short)f2b(c1.x); r[5] = (short)f2b(c1.y);
    r[6] = (short)f2b(c1.z); r[7] = (short)f2b(c1.w);
  } else {
    #pragma unroll
    for (int j = 0; j < 8; ++j) r[j] = 0;
  }
  return r;
}

__global__ void k_emb_mm(const float* __restrict__ embed,
                         const unsigned short* __restrict__ WeT,
                         unsigned short* __restrict__ Tb) {
  const int t = threadIdx.x, w = t >> 6, l = t & 63, li = l & 15, lh = l >> 4;
  const int wbase = blockIdx.x * 128 + w * 32;
  f32x4 acc[2][6];
  #pragma unroll
  for (int rt = 0; rt < 2; rt++)
    #pragma unroll
    for (int ct = 0; ct < 6; ct++) acc[rt][ct] = (f32x4)0.f;
  for (int ks = 0; ks < 10; ++ks) {
    const int ko = lh * 8 + ks * 32;
    bf16x8 aA0 = ldcvt(embed, wbase + li, ko);
    bf16x8 aA1 = ldcvt(embed, wbase + 16 + li, ko);
    #pragma unroll
    for (int ct = 0; ct < 6; ct++) {
      bf16x8 bB = *(const bf16x8*)&WeT[(ct * 16 + li) * EMB_K + ko];
      acc[0][ct] = MFMA16(aA0, bB, acc[0][ct]);
      acc[1][ct] = MFMA16(aA1, bB, acc[1][ct]);
    }
  }
  #pragma unroll
  for (int rt = 0; rt < 2; rt++)
    #pragma unroll
    for (int ct = 0; ct < 6; ct++)
      #pragma unroll
      for (int r = 0; r < 4; r++)
        Tb[(wbase + rt * 16 + lh * 4 + r) * DH + ct * 16 + li] = f2b(acc[rt][ct][r]);
}

// ---- fused gather + tanh + h/a_s/a_d (step 0); 256 thr, 128 nodes/block ----
__global__ __launch_bounds__(256) void k_gh(
    const int* __restrict__ ids, const unsigned short* __restrict__ Tb,
    const float* __restrict__ be, const unsigned short* __restrict__ WgT,
    const float* __restrict__ att_s, const float* __restrict__ att_d,
    unsigned short* __restrict__ xb, unsigned short* __restrict__ h,
    float* __restrict__ a_s, float* __restrict__ a_d) {
  __shared__ __align__(16) unsigned short sX[128 * XS];   // 26624 B
  __shared__ int s_id[128];
  __shared__ float s_be[DH];
  const int t = threadIdx.x, w = t >> 6, l = t & 63, li = l & 15, lh = l >> 4;
  const int nb0 = blockIdx.x * 128;
  bf16x8 WF[6][3];
  #pragma unroll
  for (int ct = 0; ct < 6; ++ct)
    #pragma unroll
    for (int ks = 0; ks < 3; ++ks)
      WF[ct][ks] = *(const bf16x8*)&WgT[(ct * 16 + li) * DH + lh * 8 + ks * 32];
  if (t < 128) s_id[t] = ids[nb0 + t];
  if (t < DH) s_be[t] = be[t];
  __syncthreads();
  #pragma unroll
  for (int j = 0; j < 6; ++j) {
    int idx = t + 256 * j;                 // 1536 = 128 rows x 12 chunks
    int row = idx / 12, ch = idx - row * 12;
    u16x8 v = *(const u16x8*)&Tb[s_id[row] * DH + ch * 8];
    u16x8 o;
    #pragma unroll
    for (int k = 0; k < 8; ++k) o[k] = f2b(ftanh(b2f(v[k]) + s_be[ch * 8 + k]));
    *(u16x8*)&sX[row * XS + ch * 8] = o;
    *(u16x8*)&xb[(nb0 + row) * DH + ch * 8] = o;
  }
  __syncthreads();
  const int wbase = w * 32;
  f32x4 acc[2][6];
  #pragma unroll
  for (int rt = 0; rt < 2; rt++)
    #pragma unroll
    for (int ct = 0; ct < 6; ct++) acc[rt][ct] = (f32x4)0.f;
  bf16x8 aA[2][3];
  #pragma unroll
  for (int rt = 0; rt < 2; rt++)
    #pragma unroll
    for (int ks = 0; ks < 3; ks++)
      aA[rt][ks] = *(const bf16x8*)&sX[(wbase + rt * 16 + li) * XS + lh * 8 + ks * 32];
  #pragma unroll
  for (int ks = 0; ks < 3; ++ks)
    #pragma unroll
    for (int ct = 0; ct < 6; ct++) {
      acc[0][ct] = MFMA16(aA[0][ks], WF[ct][ks], acc[0][ct]);
      acc[1][ct] = MFMA16(aA[1][ks], WF[ct][ks], acc[1][ct]);
    }
  float ps[2][4] = {}, pd[2][4] = {};
  #pragma unroll
  for (int rt = 0; rt < 2; rt++)
    #pragma unroll
    for (int ct = 0; ct < 6; ct++) {
      const int col = ct * 16 + li;
      const float as_ = att_s[col], ad_ = att_d[col];
      #pragma unroll
      for (int r = 0; r < 4; r++) {
        float v = acc[rt][ct][r];
        h[(nb0 + wbase + rt * 16 + lh * 4 + r) * DH + col] = f2b(v);
        ps[rt][r] += v * as_;
        pd[rt][r] += v * ad_;
      }
    }
  #pragma unroll
  for (int rt = 0; rt < 2; rt++)
    #pragma unroll
    for (int r = 0; r < 4; r++) {
      float s = ps[rt][r], d = pd[rt][r];
      #pragma unroll
      for (int m = 1; m < 16; m <<= 1) { s += __shfl_xor(s, m); d += __shfl_xor(d, m); }
      if (li == 0) {
        const int row = nb0 + wbase + rt * 16 + lh * 4 + r;
        a_s[row] = s;
        a_d[row] = d;
      }
    }
}

// ---- h = xb @ Wg (bf16 out) + a_s/a_d reductions (step 1; MFMA, W in LDS) ----
__global__ __launch_bounds__(256) void k_h(
    const unsigned short* __restrict__ xb, const unsigned short* __restrict__ WgT,
    const float* __restrict__ att_s, const float* __restrict__ att_d,
    unsigned short* __restrict__ h, float* __restrict__ a_s,
    float* __restrict__ a_d) {
  __shared__ __align__(16) unsigned short sW[DH * WS];   // 19200 B
  const int t = threadIdx.x, w = t >> 6, l = t & 63, li = l & 15, lh = l >> 4;
  const int wbase = blockIdx.x * 128 + w * 32;
  for (int i = t; i < DH * 12; i += 256) {
    int r = i / 12, c8 = i - r * 12;
    *(int4*)&sW[r * WS + c8 * 8] = *(const int4*)&WgT[r * DH + c8 * 8];
  }
  __syncthreads();
  f32x4 acc[2][6];
  #pragma unroll
  for (int rt = 0; rt < 2; rt++)
    #pragma unroll
    for (int ct = 0; ct < 6; ct++) acc[rt][ct] = (f32x4)0.f;
  #pragma unroll
  for (int ks = 0; ks < 3; ++ks) {
    const int ko = lh * 8 + ks * 32;
    bf16x8 aA0 = *(const bf16x8*)&xb[(wbase + li) * DH + ko];
    bf16x8 aA1 = *(const bf16x8*)&xb[(wbase + 16 + li) * DH + ko];
    #pragma unroll
    for (int ct = 0; ct < 6; ct++) {
      bf16x8 bB = *(const bf16x8*)&sW[(ct * 16 + li) * WS + ko];
      acc[0][ct] = MFMA16(aA0, bB, acc[0][ct]);
      acc[1][ct] = MFMA16(aA1, bB, acc[1][ct]);
    }
  }
  float ps[2][4] = {}, pd[2][4] = {};
  #pragma unroll
  for (int rt = 0; rt < 2; rt++)
    #pragma unroll
    for (int ct = 0; ct < 6; ct++) {
      const int col = ct * 16 + li;
      const float as_ = att_s[col], ad_ = att_d[col];
      #pragma unroll
      for (int r = 0; r < 4; r++) {
        float v = acc[rt][ct][r];
        h[(wbase + rt * 16 + lh * 4 + r) * DH + col] = f2b(v);
        ps[rt][r] += v * as_;
        pd[rt][r] += v * ad_;
      }
    }
  #pragma unroll
  for (int rt = 0; rt < 2; rt++)
    #pragma unroll
    for (int r = 0; r < 4; r++) {
      float s = ps[rt][r], d = pd[rt][r];
      #pragma unroll
      for (int m = 1; m < 16; m <<= 1) { s += __shfl_xor(s, m); d += __shfl_xor(d, m); }
      if (li == 0) {
        const int row = wbase + rt * 16 + lh * 4 + r;
        a_s[row] = s;
        a_d[row] = d;
      }
    }
}

// ---- per-graph GAT via CSR gather; 1024 thr, 4 threads/node (24 cols each) ----
__global__ __launch_bounds__(1024, 8) void k_att(
    const int* __restrict__ src, const int* __restrict__ dst,
    const unsigned short* __restrict__ h, const float* __restrict__ a_sg,
    const float* __restrict__ a_dg, const float* __restrict__ bg,
    unsigned short* __restrict__ aout) {
  __shared__ __align__(16) unsigned short sH[LGRAPH * XS];  // 53248 B
  __shared__ float s_ev[EPG];
  __shared__ unsigned char s_sl[EPG], s_dl[EPG];
  __shared__ unsigned char s_srcS[EPG];
  __shared__ int s_cnt[LGRAPH], s_off[LGRAPH], s_pos[LGRAPH];
  __shared__ float s_as[LGRAPH], s_ad[LGRAPH];
  __shared__ float s_bg[DH];
  const int g = blockIdx.x, t = threadIdx.x;
  const int nb = g * LGRAPH;
  if (t < LGRAPH) { s_cnt[t] = 0; s_as[t] = a_sg[nb + t]; s_ad[t] = a_dg[nb + t]; }
  if (t < DH) s_bg[t] = bg[t];
  #pragma unroll
  for (int j = 0; j < 3; ++j) {
    int idx = t + 1024 * j;                // 3072 = 256 rows x 12 chunks
    int row = idx / 12, ch = idx - row * 12;
    *(int4*)&sH[row * XS + ch * 8] = *(const int4*)&h[(nb + row) * DH + ch * 8];
  }
  __syncthreads();
  for (int e = t; e < EPG; e += 1024) {
    int sl = src[g * EPG + e] - nb, dl = dst[g * EPG + e] - nb;
    s_sl[e] = (unsigned char)sl;
    s_dl[e] = (unsigned char)dl;
    atomicAdd(&s_cnt[dl], 1);
  }
  __syncthreads();
  if (t < 64) {
    int carry = 0;
    #pragma unroll
    for (int c = 0; c < 4; ++c) {
      int v = s_cnt[c * 64 + t];
      int x = v;
      #pragma unroll
      for (int o = 1; o < 64; o <<= 1) {
        int y = __shfl_up(x, o);
        if (t >= o) x += y;
      }
      s_off[c * 64 + t] = x - v + carry;
      carry += __shfl(x, 63);
    }
  }
  __syncthreads();
  if (t < LGRAPH) s_pos[t] = s_off[t];
  __syncthreads();
  for (int e = t; e < EPG; e += 1024) {
    int sl = s_sl[e], dl = s_dl[e];
    float ee = s_as[sl] + s_ad[dl];
    ee = ee > 0.f ? ee : NEG * ee;
    int pos = atomicAdd(&s_pos[dl], 1);
    s_srcS[pos] = (unsigned char)sl;
    s_ev[pos] = ee;
  }
  __syncthreads();
  {
    const int d = t >> 2;
    const int cbase = (t & 3) * 24;
    const int beg = s_off[d], end = beg + s_cnt[d];
    float ss = s_as[d] + s_ad[d];
    ss = ss > 0.f ? ss : NEG * ss;
    float m = ss;
    for (int i = beg; i < end; ++i) m = fmaxf(m, s_ev[i]);
    float acc[24];
    float wself = __expf(ss - m);
    float den = wself;
    #pragma unroll
    for (int k = 0; k < 3; ++k) {
      u16x8 v = *(const u16x8*)&sH[d * XS + cbase + k * 8];
      #pragma unroll
      for (int j = 0; j < 8; ++j) acc[k * 8 + j] = wself * b2f(v[j]);
    }
    for (int i = beg; i < end; ++i) {
      float wv = __expf(s_ev[i] - m);
      den += wv;
      int sl2 = s_srcS[i];
      #pragma unroll
      for (int k = 0; k < 3; ++k) {
        u16x8 v = *(const u16x8*)&sH[sl2 * XS + cbase + k * 8];
        #pragma unroll
        for (int j = 0; j < 8; ++j) acc[k * 8 + j] += wv * b2f(v[j]);
      }
    }
    float inv = 1.f / den;
    unsigned short* op = &aout[(nb + d) * DH + cbase];
    #pragma unroll
    for (int k = 0; k < 3; ++k) {
      u16x8 o;
      #pragma unroll
      for (int j = 0; j < 8; ++j) o[j] = f2b(acc[k * 8 + j] * inv + s_bg[cbase + k * 8 + j]);
      *(u16x8*)&op[k * 8] = o;
    }
  }
}

// ---- fused GRU, BARRIER-FREE tiles: 8 waves, each owns a private 16-row slice ----
// 256 blocks x 512 thr. Weights in LDS (one barrier after stage). Each wave:
// stage-in, r/z MFMA (full 96 cols), u write, aU read, hh MFMA, xn, store-out —
// all LDS ops confined to its own rows => same-wave DS ordering, no __syncthreads.
__global__ __launch_bounds__(512, 2) void k_gru(
    const unsigned short* __restrict__ ab, unsigned short* __restrict__ xb,
    const unsigned short* __restrict__ WT, const float* __restrict__ bc) {
  __shared__ __align__(16) unsigned short sW[6 * DH * WS];   // 115200 B
  __shared__ __align__(16) unsigned short sX[128 * WS];      // 25600 B
  const int t = threadIdx.x, w = t >> 6, l = t & 63, li = l & 15, lh = l >> 4;
  // stage weights: order Wr0,Wr1,Wz0,Wz1,Wh0,Wh1 (WT idx 3,4,1,2,5,6)
  #pragma unroll
  for (int m = 0; m < 6; ++m) {
    const int srcm = (m == 0) ? 3 : (m == 1) ? 4 : (m == 2) ? 1 : (m == 3) ? 2 : (m == 4) ? 5 : 6;
    const unsigned short* srcp = WT + srcm * DH * DH;
    for (int i = t; i < DH * 12; i += 512) {
      int r = i / 12, c8 = i - r * 12;
      *(int4*)&sW[(m * DH + r) * WS + c8 * 8] = *(const int4*)&srcp[r * DH + c8 * 8];
    }
  }
  float zb_[6], rb_[6], hb_[6];
  #pragma unroll
  for (int ct = 0; ct < 6; ++ct) {
    const int col = ct * 16 + li;
    zb_[ct] = bc[col]; rb_[ct] = bc[DH + col]; hb_[ct] = bc[2 * DH + col];
  }
  __syncthreads();          // the ONLY barrier
  const int r0 = w * 16;    // wave-private row slice

  for (int tile = 0; tile < 4; ++tile) {
    const int nb0 = (blockIdx.x * 4 + tile) * 128;
    // stage own 16 rows (192 int4 chunks / 64 lanes = 3 each)
    #pragma unroll
    for (int j = 0; j < 3; ++j) {
      int idx = l + 64 * j;
      int rr = idx / 12, ch = idx - rr * 12;
      *(int4*)&sX[(r0 + rr) * WS + ch * 8] =
          *(const int4*)&xb[(nb0 + r0 + rr) * DH + ch * 8];
    }
    // fragments: a from global (L2-resident), x from own slice
    bf16x8 aA[3], aX[3];
    #pragma unroll
    for (int ks = 0; ks < 3; ks++) {
      const int ko = lh * 8 + ks * 32;
      aA[ks] = *(const bf16x8*)&ab[(nb0 + r0 + li) * DH + ko];
      aX[ks] = *(const bf16x8*)&sX[(r0 + li) * WS + ko];
    }
    float xo[6][4];
    #pragma unroll
    for (int ct = 0; ct < 6; ct++)
      #pragma unroll
      for (int r = 0; r < 4; r++)
        xo[ct][r] = b2f(sX[(r0 + lh * 4 + r) * WS + ct * 16 + li]);
    // r and z gates, full 96 cols
    f32x4 accR[6], accZ[6];
    #pragma unroll
    for (int ct = 0; ct < 6; ct++) { accR[ct] = (f32x4)0.f; accZ[ct] = (f32x4)0.f; }
    #pragma unroll
    for (int ks = 0; ks < 3; ks++) {
      const int ko = lh * 8 + ks * 32;
      #pragma unroll
      for (int ct = 0; ct < 6; ct++) {
        const int wrow = ct * 16 + li;
        bf16x8 w_r0 = *(const bf16x8*)&sW[(0 * DH + wrow) * WS + ko];
        bf16x8 w_r1 = *(const bf16x8*)&sW[(1 * DH + wrow) * WS + ko];
        bf16x8 w_z0 = *(const bf16x8*)&sW[(2 * DH + wrow) * WS + ko];
        bf16x8 w_z1 = *(const bf16x8*)&sW[(3 * DH + wrow) * WS + ko];
        accR[ct] = MFMA16(aA[ks], w_r0, accR[ct]);
        accR[ct] = MFMA16(aX[ks], w_r1, accR[ct]);
        accZ[ct] = MFMA16(aA[ks], w_z0, accZ[ct]);
        accZ[ct] = MFMA16(aX[ks], w_z1, accZ[ct]);
      }
    }
    // u = x * sigmoid(r) into own slice (no barrier: same-wave DS ordering)
    #pragma unroll
    for (int ct = 0; ct < 6; ct++) {
      const int col = ct * 16 + li;
      #pragma unroll
      for (int r = 0; r < 4; r++) {
        float rv = sigm(accR[ct][r] + rb_[ct]);
        sX[(r0 + lh * 4 + r) * WS + col] = f2b(xo[ct][r] * rv);
      }
    }
    bf16x8 aU[3];
    #pragma unroll
    for (int ks = 0; ks < 3; ks++)
      aU[ks] = *(const bf16x8*)&sX[(r0 + li) * WS + lh * 8 + ks * 32];
    f32x4 accH[6];
    #pragma unroll
    for (int ct = 0; ct < 6; ct++) accH[ct] = (f32x4)0.f;
    #pragma unroll
    for (int ks = 0; ks < 3; ks++) {
      const int ko = lh * 8 + ks * 32;
      #pragma unroll
      for (int ct = 0; ct < 6; ct++) {
        const int wrow = ct * 16 + li;
        bf16x8 w_h0 = *(const bf16x8*)&sW[(4 * DH + wrow) * WS + ko];
        bf16x8 w_h1 = *(const bf16x8*)&sW[(5 * DH + wrow) * WS + ko];
        accH[ct] = MFMA16(aA[ks], w_h0, accH[ct]);
        accH[ct] = MFMA16(aU[ks], w_h1, accH[ct]);
      }
    }
    // epilogue: xn into own slice, then coalesced store of own rows
    #pragma unroll
    for (int ct = 0; ct < 6; ct++) {
      const int col = ct * 16 + li;
      #pragma unroll
      for (int r = 0; r < 4; r++) {
        float z = sigm(accZ[ct][r] + zb_[ct]);
        float hh = ftanh(accH[ct][r] + hb_[ct]);
        float xn = hh * z + xo[ct][r] * (1.f - z);
        sX[(r0 + lh * 4 + r) * WS + col] = f2b(xn);
      }
    }
    #pragma unroll
    for (int j = 0; j < 3; ++j) {
      int idx = l + 64 * j;
      int rr = idx / 12, ch = idx - rr * 12;
      *(int4*)&xb[(nb0 + r0 + rr) * DH + ch * 8] =
          *(const int4*)&sX[(r0 + rr) * WS + ch * 8];
    }
  }
}

// ---- readout: y = tanh(xb @ Wemb); pool max+mean; out = pooled @ Wmlp ----
__global__ __launch_bounds__(256) void k_readout(
    const unsigned short* __restrict__ xb, const unsigned short* __restrict__ WembT,
    const float* __restrict__ Wmlp, float* __restrict__ out) {
  __shared__ __align__(16) unsigned short sW[DH * WS];   // 19200 B
  __shared__ float pmaxs[4][DH], psums[4][DH];
  __shared__ float spool[DH];
  const int g = blockIdx.x, t = threadIdx.x, w = t >> 6, l = t & 63, li = l & 15, lh = l >> 4;
  const int wbase = g * LGRAPH + w * 64;
  for (int i = t; i < DH * 12; i += 256) {
    int r = i / 12, c8 = i - r * 12;
    *(int4*)&sW[r * WS + c8 * 8] = *(const int4*)&WembT[r * DH + c8 * 8];
  }
  __syncthreads();
  f32x4 acc[4][6];
  #pragma unroll
  for (int rt = 0; rt < 4; rt++)
    #pragma unroll
    for (int ct = 0; ct < 6; ct++) acc[rt][ct] = (f32x4)0.f;
  #pragma unroll
  for (int ks = 0; ks < 3; ks++) {
    const int ko = lh * 8 + ks * 32;
    bf16x8 aA[4];
    #pragma unroll
    for (int rt = 0; rt < 4; rt++)
      aA[rt] = *(const bf16x8*)&xb[(wbase + rt * 16 + li) * DH + ko];
    #pragma unroll
    for (int ct = 0; ct < 6; ct++) {
      bf16x8 bB = *(const bf16x8*)&sW[(ct * 16 + li) * WS + ko];
      #pragma unroll
      for (int rt = 0; rt < 4; rt++) acc[rt][ct] = MFMA16(aA[rt], bB, acc[rt][ct]);
    }
  }
  float pm[6], psu[6];
  #pragma unroll
  for (int ct = 0; ct < 6; ct++) {
    float mx = -1e30f, sm = 0.f;
    #pragma unroll
    for (int rt = 0; rt < 4; rt++)
      #pragma unroll
      for (int r = 0; r < 4; r++) {
        float y = ftanh(acc[rt][ct][r]);
        mx = fmaxf(mx, y);
        sm += y;
      }
    pm[ct] = mx; psu[ct] = sm;
  }
  #pragma unroll
  for (int ct = 0; ct < 6; ct++) {
    pm[ct] = fmaxf(pm[ct], __shfl_xor(pm[ct], 16));
    psu[ct] += __shfl_xor(psu[ct], 16);
    pm[ct] = fmaxf(pm[ct], __shfl_xor(pm[ct], 32));
    psu[ct] += __shfl_xor(psu[ct], 32);
  }
  if (lh == 0) {
    #pragma unroll
    for (int ct = 0; ct < 6; ct++) {
      pmaxs[w][ct * 16 + li] = pm[ct];
      psums[w][ct * 16 + li] = psu[ct];
    }
  }
  __syncthreads();
  if (t < DH) {
    float mx = fmaxf(fmaxf(pmaxs[0][t], pmaxs[1][t]), fmaxf(pmaxs[2][t], pmaxs[3][t]));
    float sm = psums[0][t] + psums[1][t] + psums[2][t] + psums[3][t];
    spool[t] = mx + sm * (1.f / LGRAPH);
  }
  __syncthreads();
  if (t < NCLS) {
    float a = 0.f;
    for (int k = 0; k < DH; ++k) a += spool[k] * Wmlp[k * NCLS + t];
    out[g * NCLS + t] = a;
  }
}

extern "C" void kernel_launch(void* const* d_in, const int* in_sizes, int n_in,
                              void* d_out, int out_size, void* d_ws, size_t ws_size,
                              hipStream_t stream) {
  const int*   node_ids = (const int*)d_in[0];
  const int*   src      = (const int*)d_in[1];
  const int*   dst      = (const int*)d_in[2];
  const float* embed    = (const float*)d_in[3];
  const float* We   = (const float*)d_in[4];
  const float* be   = (const float*)d_in[5];
  const float* Wg   = (const float*)d_in[6];
  const float* att_src = (const float*)d_in[7];
  const float* att_dst = (const float*)d_in[8];
  const float* bg   = (const float*)d_in[9];
  const float* Wz0  = (const float*)d_in[10];
  const float* bz0  = (const float*)d_in[11];
  const float* Wz1  = (const float*)d_in[12];
  const float* bz1  = (const float*)d_in[13];
  const float* Wr0  = (const float*)d_in[14];
  const float* br0  = (const float*)d_in[15];
  const float* Wr1  = (const float*)d_in[16];
  const float* br1  = (const float*)d_in[17];
  const float* Wh0  = (const float*)d_in[18];
  const float* bh0  = (const float*)d_in[19];
  const float* Wh1  = (const float*)d_in[20];
  const float* bh1  = (const float*)d_in[21];
  const float* Wemb = (const float*)d_in[22];
  const float* Wmlp = (const float*)d_in[23];
  float* out = (float*)d_out;

  char* w_ = (char*)d_ws;
  unsigned short* xb   = (unsigned short*)(w_ + 0);           // 25,165,824 B
  unsigned short* ab   = (unsigned short*)(w_ + 25165824);    // 25,165,824 B
  unsigned short* h    = (unsigned short*)(w_ + 50331648);    // 25,165,824 B
  unsigned short* Tb   = (unsigned short*)(w_ + 75497472);    // 9,609,216 B
  float*          a_s  = (float*)(w_ + 85106688);             // 524,288 B
  float*          a_d  = (float*)(w_ + 85630976);             // 524,288 B
  unsigned short* WT   = (unsigned short*)(w_ + 86155264);    // 147,456 B
  unsigned short* WeT  = (unsigned short*)(w_ + 86302720);    // 61,440 B
  float*          bc   = (float*)(w_ + 86364160);             // 1,152 B

  unsigned short* WgT   = WT + 0 * DH * DH;
  unsigned short* WembT = WT + 7 * DH * DH;

  hipLaunchKernelGGL(k_prep_w, dim3(10), dim3(256), 0, stream,
                     Wg, Wz0, Wz1, Wr0, Wr1, Wh0, Wh1, Wemb, We,
                     bz0, bz1, br0, br1, bh0, bh1, WT, WeT, bc);
  hipLaunchKernelGGL(k_emb_mm, dim3(EMB_ROWS / 128), dim3(256), 0, stream, embed, WeT, Tb);
  hipLaunchKernelGGL(k_gh, dim3(NNODES / 128), dim3(256), 0, stream,
                     node_ids, Tb, be, WgT, att_src, att_dst, xb, h, a_s, a_d);
  hipLaunchKernelGGL(k_att, dim3(BGRAPH), dim3(1024), 0, stream,
                     src, dst, h, a_s, a_d, bg, ab);
  hipLaunchKernelGGL(k_gru, dim3(256), dim3(512), 0, stream, ab, xb, WT, bc);
  hipLaunchKernelGGL(k_h, dim3(NNODES / 128), dim3(256), 0, stream,
                     xb, WgT, att_src, att_dst, h, a_s, a_d);
  hipLaunchKernelGGL(k_att, dim3(BGRAPH), dim3(1024), 0, stream,
                     src, dst, h, a_s, a_d, bg, ab);
  hipLaunchKernelGGL(k_gru, dim3(256), dim3(512), 0, stream, ab, xb, WT, bc);
  hipLaunchKernelGGL(k_readout, dim3(BGRAPH), dim3(256), 0, stream, xb, WembT, Wmlp, out);
}

// Round 11
// 254.406 us; speedup vs baseline: 1.8671x; 1.8671x over previous
//
#include <hip/hip_runtime.h>
#include <hip/hip_bf16.h>

#define NNODES 131072
#define LGRAPH 256
#define BGRAPH 512
#define DIN 300
#define DH 96
#define EPG 2048
#define VOCAB 50001
#define NCLS 20
#define NEG 0.2f
#define EMB_ROWS 50048   // VOCAB padded to 128-row tiles
#define EMB_K 320        // 300 padded to 32-multiple
#define ES 328           // padded LDS stride (halfs) for staged embed tile
#define WS 100           // padded LDS stride (halfs), conflict-free for b128
#define XS 104           // padded LDS stride (halfs) for x/h tiles

typedef __attribute__((ext_vector_type(4))) float f32x4;
typedef __attribute__((ext_vector_type(8))) short bf16x8;
typedef __attribute__((ext_vector_type(8))) unsigned short u16x8;
#define MFMA16(a, b, c) __builtin_amdgcn_mfma_f32_16x16x32_bf16(a, b, c, 0, 0, 0)

__device__ __forceinline__ unsigned short f2b(float f) {
  __hip_bfloat16 h = __float2bfloat16(f);
  return *reinterpret_cast<unsigned short*>(&h);
}
__device__ __forceinline__ float b2f(unsigned short u) {
  unsigned v = ((unsigned)u) << 16;
  return __uint_as_float(v);
}
__device__ __forceinline__ float sigm(float v) { return 1.f / (1.f + __expf(-v)); }
__device__ __forceinline__ float ftanh(float x) {
  float ax = fabsf(x);
  float e = __expf(ax + ax);
  float t = 1.f - 2.f / (e + 1.f);
  return copysignf(t, x);
}

// ---- weight prep: W[k][c] f32 -> WT[c][k] bf16 ; WeT ; combined biases ----
__global__ void k_prep_w(const float* __restrict__ Wg, const float* __restrict__ Wz0,
                         const float* __restrict__ Wz1, const float* __restrict__ Wr0,
                         const float* __restrict__ Wr1, const float* __restrict__ Wh0,
                         const float* __restrict__ Wh1, const float* __restrict__ Wemb,
                         const float* __restrict__ We,
                         const float* __restrict__ bz0, const float* __restrict__ bz1,
                         const float* __restrict__ br0, const float* __restrict__ br1,
                         const float* __restrict__ bh0, const float* __restrict__ bh1,
                         unsigned short* __restrict__ WT, unsigned short* __restrict__ WeT,
                         float* __restrict__ bc) {
  const int b = blockIdx.x, t = threadIdx.x;
  if (b < 8) {
    const float* src = (b == 0) ? Wg : (b == 1) ? Wz0 : (b == 2) ? Wz1 : (b == 3) ? Wr0
                     : (b == 4) ? Wr1 : (b == 5) ? Wh0 : (b == 6) ? Wh1 : Wemb;
    unsigned short* dst = WT + b * DH * DH;
    for (int i = t; i < DH * DH; i += 256) {
      int c = i / DH, k = i - c * DH;
      dst[i] = f2b(src[k * DH + c]);
    }
  } else if (b == 8) {
    for (int i = t; i < DH * EMB_K; i += 256) {
      int c = i / EMB_K, k = i - c * EMB_K;
      WeT[i] = (k < DIN) ? f2b(We[k * DH + c]) : (unsigned short)0;
    }
  } else {
    if (t < DH) {
      bc[t] = bz0[t] + bz1[t];
      bc[DH + t] = br0[t] + br1[t];
      bc[2 * DH + t] = bh0[t] + bh1[t];
    }
  }
}

// ---- Tb = embed @ We  (MFMA, M-tile 128, coalesced LDS-staged A, bf16 out) ----
// 512 thr, 8 waves. Stage: 128 rows x 300 f32 coalesced float4 -> bf16 LDS
// (stride ES=328 -> 2-way bank aliasing only). MFMA: wave w rows w*16..+16.
__global__ __launch_bounds__(512) void k_emb_mm(
    const float* __restrict__ embed, const unsigned short* __restrict__ WeT,
    unsigned short* __restrict__ Tb) {
  __shared__ __align__(16) unsigned short sE[128 * ES];   // 83968 B
  const int t = threadIdx.x, w = t >> 6, l = t & 63, li = l & 15, lh = l >> 4;
  const int rbase = blockIdx.x * 128;
  // zero the K-pad [300,320)
  for (int idx = t; idx < 128 * 20; idx += 512) {
    int row = idx / 20, k = 300 + (idx - (idx / 20) * 20);
    sE[row * ES + k] = 0;
  }
  // coalesced stage: 9600 float4 chunks (128 rows x 75)
  for (int idx = t; idx < 9600; idx += 512) {
    int row = idx / 75, c4 = idx - row * 75;
    int gr = rbase + row;
    float4 v = (gr < VOCAB) ? *(const float4*)&embed[gr * DIN + c4 * 4]
                            : make_float4(0.f, 0.f, 0.f, 0.f);
    ushort4 o;
    o.x = f2b(v.x); o.y = f2b(v.y); o.z = f2b(v.z); o.w = f2b(v.w);
    *(ushort4*)&sE[row * ES + c4 * 4] = o;
  }
  __syncthreads();
  const int r0 = w * 16;
  f32x4 acc[6];
  #pragma unroll
  for (int ct = 0; ct < 6; ct++) acc[ct] = (f32x4)0.f;
  for (int ks = 0; ks < 10; ++ks) {
    const int ko = lh * 8 + ks * 32;
    bf16x8 aA = *(const bf16x8*)&sE[(r0 + li) * ES + ko];
    #pragma unroll
    for (int ct = 0; ct < 6; ct++) {
      bf16x8 bB = *(const bf16x8*)&WeT[(ct * 16 + li) * EMB_K + ko];
      acc[ct] = MFMA16(aA, bB, acc[ct]);
    }
  }
  #pragma unroll
  for (int ct = 0; ct < 6; ct++)
    #pragma unroll
    for (int r = 0; r < 4; r++)
      Tb[(rbase + r0 + lh * 4 + r) * DH + ct * 16 + li] = f2b(acc[ct][r]);
}

// ---- fused gather + tanh + h/a_s/a_d (step 0); 256 thr, 128 nodes/block ----
__global__ __launch_bounds__(256) void k_gh(
    const int* __restrict__ ids, const unsigned short* __restrict__ Tb,
    const float* __restrict__ be, const unsigned short* __restrict__ WgT,
    const float* __restrict__ att_s, const float* __restrict__ att_d,
    unsigned short* __restrict__ xb, unsigned short* __restrict__ h,
    float* __restrict__ a_s, float* __restrict__ a_d) {
  __shared__ __align__(16) unsigned short sX[128 * XS];   // 26624 B
  __shared__ int s_id[128];
  __shared__ float s_be[DH];
  const int t = threadIdx.x, w = t >> 6, l = t & 63, li = l & 15, lh = l >> 4;
  const int nb0 = blockIdx.x * 128;
  bf16x8 WF[6][3];
  #pragma unroll
  for (int ct = 0; ct < 6; ++ct)
    #pragma unroll
    for (int ks = 0; ks < 3; ++ks)
      WF[ct][ks] = *(const bf16x8*)&WgT[(ct * 16 + li) * DH + lh * 8 + ks * 32];
  if (t < 128) s_id[t] = ids[nb0 + t];
  if (t < DH) s_be[t] = be[t];
  __syncthreads();
  #pragma unroll
  for (int j = 0; j < 6; ++j) {
    int idx = t + 256 * j;                 // 1536 = 128 rows x 12 chunks
    int row = idx / 12, ch = idx - row * 12;
    u16x8 v = *(const u16x8*)&Tb[s_id[row] * DH + ch * 8];
    u16x8 o;
    #pragma unroll
    for (int k = 0; k < 8; ++k) o[k] = f2b(ftanh(b2f(v[k]) + s_be[ch * 8 + k]));
    *(u16x8*)&sX[row * XS + ch * 8] = o;
    *(u16x8*)&xb[(nb0 + row) * DH + ch * 8] = o;
  }
  __syncthreads();
  const int wbase = w * 32;
  f32x4 acc[2][6];
  #pragma unroll
  for (int rt = 0; rt < 2; rt++)
    #pragma unroll
    for (int ct = 0; ct < 6; ct++) acc[rt][ct] = (f32x4)0.f;
  bf16x8 aA[2][3];
  #pragma unroll
  for (int rt = 0; rt < 2; rt++)
    #pragma unroll
    for (int ks = 0; ks < 3; ks++)
      aA[rt][ks] = *(const bf16x8*)&sX[(wbase + rt * 16 + li) * XS + lh * 8 + ks * 32];
  #pragma unroll
  for (int ks = 0; ks < 3; ++ks)
    #pragma unroll
    for (int ct = 0; ct < 6; ct++) {
      acc[0][ct] = MFMA16(aA[0][ks], WF[ct][ks], acc[0][ct]);
      acc[1][ct] = MFMA16(aA[1][ks], WF[ct][ks], acc[1][ct]);
    }
  float ps[2][4] = {}, pd[2][4] = {};
  #pragma unroll
  for (int rt = 0; rt < 2; rt++)
    #pragma unroll
    for (int ct = 0; ct < 6; ct++) {
      const int col = ct * 16 + li;
      const float as_ = att_s[col], ad_ = att_d[col];
      #pragma unroll
      for (int r = 0; r < 4; r++) {
        float v = acc[rt][ct][r];
        h[(nb0 + wbase + rt * 16 + lh * 4 + r) * DH + col] = f2b(v);
        ps[rt][r] += v * as_;
        pd[rt][r] += v * ad_;
      }
    }
  #pragma unroll
  for (int rt = 0; rt < 2; rt++)
    #pragma unroll
    for (int r = 0; r < 4; r++) {
      float s = ps[rt][r], d = pd[rt][r];
      #pragma unroll
      for (int m = 1; m < 16; m <<= 1) { s += __shfl_xor(s, m); d += __shfl_xor(d, m); }
      if (li == 0) {
        const int row = nb0 + wbase + rt * 16 + lh * 4 + r;
        a_s[row] = s;
        a_d[row] = d;
      }
    }
}

// ---- h = xb @ Wg (bf16 out) + a_s/a_d reductions (step 1; MFMA, W in LDS) ----
__global__ __launch_bounds__(256) void k_h(
    const unsigned short* __restrict__ xb, const unsigned short* __restrict__ WgT,
    const float* __restrict__ att_s, const float* __restrict__ att_d,
    unsigned short* __restrict__ h, float* __restrict__ a_s,
    float* __restrict__ a_d) {
  __shared__ __align__(16) unsigned short sW[DH * WS];   // 19200 B
  const int t = threadIdx.x, w = t >> 6, l = t & 63, li = l & 15, lh = l >> 4;
  const int wbase = blockIdx.x * 128 + w * 32;
  for (int i = t; i < DH * 12; i += 256) {
    int r = i / 12, c8 = i - r * 12;
    *(int4*)&sW[r * WS + c8 * 8] = *(const int4*)&WgT[r * DH + c8 * 8];
  }
  __syncthreads();
  f32x4 acc[2][6];
  #pragma unroll
  for (int rt = 0; rt < 2; rt++)
    #pragma unroll
    for (int ct = 0; ct < 6; ct++) acc[rt][ct] = (f32x4)0.f;
  #pragma unroll
  for (int ks = 0; ks < 3; ++ks) {
    const int ko = lh * 8 + ks * 32;
    bf16x8 aA0 = *(const bf16x8*)&xb[(wbase + li) * DH + ko];
    bf16x8 aA1 = *(const bf16x8*)&xb[(wbase + 16 + li) * DH + ko];
    #pragma unroll
    for (int ct = 0; ct < 6; ct++) {
      bf16x8 bB = *(const bf16x8*)&sW[(ct * 16 + li) * WS + ko];
      acc[0][ct] = MFMA16(aA0, bB, acc[0][ct]);
      acc[1][ct] = MFMA16(aA1, bB, acc[1][ct]);
    }
  }
  float ps[2][4] = {}, pd[2][4] = {};
  #pragma unroll
  for (int rt = 0; rt < 2; rt++)
    #pragma unroll
    for (int ct = 0; ct < 6; ct++) {
      const int col = ct * 16 + li;
      const float as_ = att_s[col], ad_ = att_d[col];
      #pragma unroll
      for (int r = 0; r < 4; r++) {
        float v = acc[rt][ct][r];
        h[(wbase + rt * 16 + lh * 4 + r) * DH + col] = f2b(v);
        ps[rt][r] += v * as_;
        pd[rt][r] += v * ad_;
      }
    }
  #pragma unroll
  for (int rt = 0; rt < 2; rt++)
    #pragma unroll
    for (int r = 0; r < 4; r++) {
      float s = ps[rt][r], d = pd[rt][r];
      #pragma unroll
      for (int m = 1; m < 16; m <<= 1) { s += __shfl_xor(s, m); d += __shfl_xor(d, m); }
      if (li == 0) {
        const int row = wbase + rt * 16 + lh * 4 + r;
        a_s[row] = s;
        a_d[row] = d;
      }
    }
}

// ---- per-graph GAT via CSR gather; 512 thr, 2 threads/node (48 cols each) ----
__global__ __launch_bounds__(512, 4) void k_att(
    const int* __restrict__ src, const int* __restrict__ dst,
    const unsigned short* __restrict__ h, const float* __restrict__ a_sg,
    const float* __restrict__ a_dg, const float* __restrict__ bg,
    unsigned short* __restrict__ aout) {
  __shared__ __align__(16) unsigned short sH[LGRAPH * XS];  // 53248 B
  __shared__ float s_ev[EPG];
  __shared__ unsigned char s_sl[EPG], s_dl[EPG];
  __shared__ unsigned char s_srcS[EPG];
  __shared__ int s_cnt[LGRAPH], s_off[LGRAPH], s_pos[LGRAPH];
  __shared__ float s_as[LGRAPH], s_ad[LGRAPH];
  __shared__ float s_bg[DH];
  const int g = blockIdx.x, t = threadIdx.x;
  const int nb = g * LGRAPH;
  if (t < LGRAPH) { s_cnt[t] = 0; s_as[t] = a_sg[nb + t]; s_ad[t] = a_dg[nb + t]; }
  if (t < DH) s_bg[t] = bg[t];
  #pragma unroll
  for (int j = 0; j < 6; ++j) {
    int idx = t + 512 * j;
    int row = idx / 12, ch = idx - row * 12;
    *(int4*)&sH[row * XS + ch * 8] = *(const int4*)&h[(nb + row) * DH + ch * 8];
  }
  __syncthreads();
  for (int e = t; e < EPG; e += 512) {
    int sl = src[g * EPG + e] - nb, dl = dst[g * EPG + e] - nb;
    s_sl[e] = (unsigned char)sl;
    s_dl[e] = (unsigned char)dl;
    atomicAdd(&s_cnt[dl], 1);
  }
  __syncthreads();
  if (t < 64) {
    int carry = 0;
    #pragma unroll
    for (int c = 0; c < 4; ++c) {
      int v = s_cnt[c * 64 + t];
      int x = v;
      #pragma unroll
      for (int o = 1; o < 64; o <<= 1) {
        int y = __shfl_up(x, o);
        if (t >= o) x += y;
      }
      s_off[c * 64 + t] = x - v + carry;
      carry += __shfl(x, 63);
    }
  }
  __syncthreads();
  if (t < LGRAPH) s_pos[t] = s_off[t];
  __syncthreads();
  for (int e = t; e < EPG; e += 512) {
    int sl = s_sl[e], dl = s_dl[e];
    float ee = s_as[sl] + s_ad[dl];
    ee = ee > 0.f ? ee : NEG * ee;
    int pos = atomicAdd(&s_pos[dl], 1);
    s_srcS[pos] = (unsigned char)sl;
    s_ev[pos] = ee;
  }
  __syncthreads();
  {
    const int d = t >> 1, half = t & 1;
    const int beg = s_off[d], end = beg + s_cnt[d];
    float ss = s_as[d] + s_ad[d];
    ss = ss > 0.f ? ss : NEG * ss;
    float m = ss;
    for (int i = beg; i < end; ++i) m = fmaxf(m, s_ev[i]);
    const int cbase = half * 48;
    float acc[48];
    float wself = __expf(ss - m);
    float den = wself;
    #pragma unroll
    for (int k = 0; k < 6; ++k) {
      u16x8 v = *(const u16x8*)&sH[d * XS + cbase + k * 8];
      #pragma unroll
      for (int j = 0; j < 8; ++j) acc[k * 8 + j] = wself * b2f(v[j]);
    }
    for (int i = beg; i < end; ++i) {
      float wv = __expf(s_ev[i] - m);
      den += wv;
      int sl2 = s_srcS[i];
      #pragma unroll
      for (int k = 0; k < 6; ++k) {
        u16x8 v = *(const u16x8*)&sH[sl2 * XS + cbase + k * 8];
        #pragma unroll
        for (int j = 0; j < 8; ++j) acc[k * 8 + j] += wv * b2f(v[j]);
      }
    }
    float inv = 1.f / den;
    unsigned short* op = &aout[(nb + d) * DH + cbase];
    #pragma unroll
    for (int k = 0; k < 6; ++k) {
      u16x8 o;
      #pragma unroll
      for (int j = 0; j < 8; ++j) o[j] = f2b(acc[k * 8 + j] * inv + s_bg[cbase + k * 8 + j]);
      *(u16x8*)&op[k * 8] = o;
    }
  }
}

// ---- fused GRU, persistent blocks, weights in LDS, 12 waves (4 rows x 3 cols) ----
// 256 blocks x 768 thr; wave wr=w/3 rows wr*32..+32, wc=w%3 cols wc*32..+32.
__global__ __launch_bounds__(768, 3) void k_gru(
    const unsigned short* __restrict__ ab, unsigned short* __restrict__ xb,
    const unsigned short* __restrict__ WT, const float* __restrict__ bc) {
  __shared__ __align__(16) unsigned short sW[6 * DH * WS];   // 115200 B
  __shared__ __align__(16) unsigned short sX[128 * WS];      // 25600 B
  const int t = threadIdx.x, w = t >> 6, l = t & 63, li = l & 15, lh = l >> 4;
  const int wr = w / 3, wc = w - wr * 3;
  // stage weights: order Wr0,Wr1,Wz0,Wz1,Wh0,Wh1 (WT idx 3,4,1,2,5,6)
  #pragma unroll
  for (int m = 0; m < 6; ++m) {
    const int srcm = (m == 0) ? 3 : (m == 1) ? 4 : (m == 2) ? 1 : (m == 3) ? 2 : (m == 4) ? 5 : 6;
    const unsigned short* srcp = WT + srcm * DH * DH;
    for (int i = t; i < DH * 12; i += 768) {
      int r = i / 12, c8 = i - r * 12;
      *(int4*)&sW[(m * DH + r) * WS + c8 * 8] = *(const int4*)&srcp[r * DH + c8 * 8];
    }
  }
  float zb_[2], rb_[2], hb_[2];
  #pragma unroll
  for (int ct = 0; ct < 2; ++ct) {
    const int col = wc * 32 + ct * 16 + li;
    zb_[ct] = bc[col]; rb_[ct] = bc[DH + col]; hb_[ct] = bc[2 * DH + col];
  }

  for (int tile = 0; tile < 4; ++tile) {
    const int nb0 = (blockIdx.x * 4 + tile) * 128;
    __syncthreads();   // sX free
    #pragma unroll
    for (int j = 0; j < 2; ++j) {
      int idx = t + 768 * j;
      int row = idx / 12, ch = idx - row * 12;
      *(int4*)&sX[row * WS + ch * 8] = *(const int4*)&xb[(nb0 + row) * DH + ch * 8];
    }
    __syncthreads();
    bf16x8 aA[2][3], aX[2][3];
    #pragma unroll
    for (int rt = 0; rt < 2; rt++)
      #pragma unroll
      for (int ks = 0; ks < 3; ks++) {
        const int row = wr * 32 + rt * 16 + li;
        const int ko = lh * 8 + ks * 32;
        aA[rt][ks] = *(const bf16x8*)&ab[(nb0 + row) * DH + ko];
        aX[rt][ks] = *(const bf16x8*)&sX[row * WS + ko];
      }
    float xo[2][2][4];
    #pragma unroll
    for (int rt = 0; rt < 2; rt++)
      #pragma unroll
      for (int ct = 0; ct < 2; ct++)
        #pragma unroll
        for (int r = 0; r < 4; r++)
          xo[rt][ct][r] = b2f(sX[(wr * 32 + rt * 16 + lh * 4 + r) * WS + wc * 32 + ct * 16 + li]);
    f32x4 accR[2][2], accZ[2][2];
    #pragma unroll
    for (int rt = 0; rt < 2; rt++)
      #pragma unroll
      for (int ct = 0; ct < 2; ct++) { accR[rt][ct] = (f32x4)0.f; accZ[rt][ct] = (f32x4)0.f; }
    #pragma unroll
    for (int ks = 0; ks < 3; ks++) {
      const int ko = lh * 8 + ks * 32;
      #pragma unroll
      for (int ct = 0; ct < 2; ct++) {
        const int wrow = wc * 32 + ct * 16 + li;
        bf16x8 w_r0 = *(const bf16x8*)&sW[(0 * DH + wrow) * WS + ko];
        bf16x8 w_r1 = *(const bf16x8*)&sW[(1 * DH + wrow) * WS + ko];
        bf16x8 w_z0 = *(const bf16x8*)&sW[(2 * DH + wrow) * WS + ko];
        bf16x8 w_z1 = *(const bf16x8*)&sW[(3 * DH + wrow) * WS + ko];
        #pragma unroll
        for (int rt = 0; rt < 2; rt++) {
          accR[rt][ct] = MFMA16(aA[rt][ks], w_r0, accR[rt][ct]);
          accR[rt][ct] = MFMA16(aX[rt][ks], w_r1, accR[rt][ct]);
          accZ[rt][ct] = MFMA16(aA[rt][ks], w_z0, accZ[rt][ct]);
          accZ[rt][ct] = MFMA16(aX[rt][ks], w_z1, accZ[rt][ct]);
        }
      }
    }
    __syncthreads();   // all sX reads done
    #pragma unroll
    for (int rt = 0; rt < 2; rt++)
      #pragma unroll
      for (int ct = 0; ct < 2; ct++) {
        const int col = wc * 32 + ct * 16 + li;
        #pragma unroll
        for (int r = 0; r < 4; r++) {
          float rv = sigm(accR[rt][ct][r] + rb_[ct]);
          sX[(wr * 32 + rt * 16 + lh * 4 + r) * WS + col] = f2b(xo[rt][ct][r] * rv);
        }
      }
    __syncthreads();   // u visible
    bf16x8 aU[2][3];
    #pragma unroll
    for (int rt = 0; rt < 2; rt++)
      #pragma unroll
      for (int ks = 0; ks < 3; ks++)
        aU[rt][ks] = *(const bf16x8*)&sX[(wr * 32 + rt * 16 + li) * WS + lh * 8 + ks * 32];
    __syncthreads();   // aU reads done before xn overwrite
    f32x4 accH[2][2];
    #pragma unroll
    for (int rt = 0; rt < 2; rt++)
      #pragma unroll
      for (int ct = 0; ct < 2; ct++) accH[rt][ct] = (f32x4)0.f;
    #pragma unroll
    for (int ks = 0; ks < 3; ks++) {
      const int ko = lh * 8 + ks * 32;
      #pragma unroll
      for (int ct = 0; ct < 2; ct++) {
        const int wrow = wc * 32 + ct * 16 + li;
        bf16x8 w_h0 = *(const bf16x8*)&sW[(4 * DH + wrow) * WS + ko];
        bf16x8 w_h1 = *(const bf16x8*)&sW[(5 * DH + wrow) * WS + ko];
        #pragma unroll
        for (int rt = 0; rt < 2; rt++) {
          accH[rt][ct] = MFMA16(aA[rt][ks], w_h0, accH[rt][ct]);
          accH[rt][ct] = MFMA16(aU[rt][ks], w_h1, accH[rt][ct]);
        }
      }
    }
    #pragma unroll
    for (int rt = 0; rt < 2; rt++)
      #pragma unroll
      for (int ct = 0; ct < 2; ct++) {
        const int col = wc * 32 + ct * 16 + li;
        #pragma unroll
        for (int r = 0; r < 4; r++) {
          float z = sigm(accZ[rt][ct][r] + zb_[ct]);
          float hh = ftanh(accH[rt][ct][r] + hb_[ct]);
          float xn = hh * z + xo[rt][ct][r] * (1.f - z);
          sX[(wr * 32 + rt * 16 + lh * 4 + r) * WS + col] = f2b(xn);
        }
      }
    __syncthreads();
    #pragma unroll
    for (int j = 0; j < 2; ++j) {
      int idx = t + 768 * j;
      int row = idx / 12, ch = idx - row * 12;
      *(int4*)&xb[(nb0 + row) * DH + ch * 8] = *(const int4*)&sX[row * WS + ch * 8];
    }
  }
}

// ---- readout: y = tanh(xb @ Wemb); pool max+mean; out = pooled @ Wmlp ----
__global__ __launch_bounds__(256) void k_readout(
    const unsigned short* __restrict__ xb, const unsigned short* __restrict__ WembT,
    const float* __restrict__ Wmlp, float* __restrict__ out) {
  __shared__ __align__(16) unsigned short sW[DH * WS];   // 19200 B
  __shared__ float pmaxs[4][DH], psums[4][DH];
  __shared__ float spool[DH];
  const int g = blockIdx.x, t = threadIdx.x, w = t >> 6, l = t & 63, li = l & 15, lh = l >> 4;
  const int wbase = g * LGRAPH + w * 64;
  for (int i = t; i < DH * 12; i += 256) {
    int r = i / 12, c8 = i - r * 12;
    *(int4*)&sW[r * WS + c8 * 8] = *(const int4*)&WembT[r * DH + c8 * 8];
  }
  __syncthreads();
  f32x4 acc[4][6];
  #pragma unroll
  for (int rt = 0; rt < 4; rt++)
    #pragma unroll
    for (int ct = 0; ct < 6; ct++) acc[rt][ct] = (f32x4)0.f;
  #pragma unroll
  for (int ks = 0; ks < 3; ks++) {
    const int ko = lh * 8 + ks * 32;
    bf16x8 aA[4];
    #pragma unroll
    for (int rt = 0; rt < 4; rt++)
      aA[rt] = *(const bf16x8*)&xb[(wbase + rt * 16 + li) * DH + ko];
    #pragma unroll
    for (int ct = 0; ct < 6; ct++) {
      bf16x8 bB = *(const bf16x8*)&sW[(ct * 16 + li) * WS + ko];
      #pragma unroll
      for (int rt = 0; rt < 4; rt++) acc[rt][ct] = MFMA16(aA[rt], bB, acc[rt][ct]);
    }
  }
  float pm[6], psu[6];
  #pragma unroll
  for (int ct = 0; ct < 6; ct++) {
    float mx = -1e30f, sm = 0.f;
    #pragma unroll
    for (int rt = 0; rt < 4; rt++)
      #pragma unroll
      for (int r = 0; r < 4; r++) {
        float y = ftanh(acc[rt][ct][r]);
        mx = fmaxf(mx, y);
        sm += y;
      }
    pm[ct] = mx; psu[ct] = sm;
  }
  #pragma unroll
  for (int ct = 0; ct < 6; ct++) {
    pm[ct] = fmaxf(pm[ct], __shfl_xor(pm[ct], 16));
    psu[ct] += __shfl_xor(psu[ct], 16);
    pm[ct] = fmaxf(pm[ct], __shfl_xor(pm[ct], 32));
    psu[ct] += __shfl_xor(psu[ct], 32);
  }
  if (lh == 0) {
    #pragma unroll
    for (int ct = 0; ct < 6; ct++) {
      pmaxs[w][ct * 16 + li] = pm[ct];
      psums[w][ct * 16 + li] = psu[ct];
    }
  }
  __syncthreads();
  if (t < DH) {
    float mx = fmaxf(fmaxf(pmaxs[0][t], pmaxs[1][t]), fmaxf(pmaxs[2][t], pmaxs[3][t]));
    float sm = psums[0][t] + psums[1][t] + psums[2][t] + psums[3][t];
    spool[t] = mx + sm * (1.f / LGRAPH);
  }
  __syncthreads();
  if (t < NCLS) {
    float a = 0.f;
    for (int k = 0; k < DH; ++k) a += spool[k] * Wmlp[k * NCLS + t];
    out[g * NCLS + t] = a;
  }
}

extern "C" void kernel_launch(void* const* d_in, const int* in_sizes, int n_in,
                              void* d_out, int out_size, void* d_ws, size_t ws_size,
                              hipStream_t stream) {
  const int*   node_ids = (const int*)d_in[0];
  const int*   src      = (const int*)d_in[1];
  const int*   dst      = (const int*)d_in[2];
  const float* embed    = (const float*)d_in[3];
  const float* We   = (const float*)d_in[4];
  const float* be   = (const float*)d_in[5];
  const float* Wg   = (const float*)d_in[6];
  const float* att_src = (const float*)d_in[7];
  const float* att_dst = (const float*)d_in[8];
  const float* bg   = (const float*)d_in[9];
  const float* Wz0  = (const float*)d_in[10];
  const float* bz0  = (const float*)d_in[11];
  const float* Wz1  = (const float*)d_in[12];
  const float* bz1  = (const float*)d_in[13];
  const float* Wr0  = (const float*)d_in[14];
  const float* br0  = (const float*)d_in[15];
  const float* Wr1  = (const float*)d_in[16];
  const float* br1  = (const float*)d_in[17];
  const float* Wh0  = (const float*)d_in[18];
  const float* bh0  = (const float*)d_in[19];
  const float* Wh1  = (const float*)d_in[20];
  const float* bh1  = (const float*)d_in[21];
  const float* Wemb = (const float*)d_in[22];
  const float* Wmlp = (const float*)d_in[23];
  float* out = (float*)d_out;

  char* w_ = (char*)d_ws;
  unsigned short* xb   = (unsigned short*)(w_ + 0);           // 25,165,824 B
  unsigned short* ab   = (unsigned short*)(w_ + 25165824);    // 25,165,824 B
  unsigned short* h    = (unsigned short*)(w_ + 50331648);    // 25,165,824 B
  unsigned short* Tb   = (unsigned short*)(w_ + 75497472);    // 9,609,216 B
  float*          a_s  = (float*)(w_ + 85106688);             // 524,288 B
  float*          a_d  = (float*)(w_ + 85630976);             // 524,288 B
  unsigned short* WT   = (unsigned short*)(w_ + 86155264);    // 147,456 B
  unsigned short* WeT  = (unsigned short*)(w_ + 86302720);    // 61,440 B
  float*          bc   = (float*)(w_ + 86364160);             // 1,152 B

  unsigned short* WgT   = WT + 0 * DH * DH;
  unsigned short* WembT = WT + 7 * DH * DH;

  hipLaunchKernelGGL(k_prep_w, dim3(10), dim3(256), 0, stream,
                     Wg, Wz0, Wz1, Wr0, Wr1, Wh0, Wh1, Wemb, We,
                     bz0, bz1, br0, br1, bh0, bh1, WT, WeT, bc);
  hipLaunchKernelGGL(k_emb_mm, dim3(EMB_ROWS / 128), dim3(512), 0, stream, embed, WeT, Tb);
  hipLaunchKernelGGL(k_gh, dim3(NNODES / 128), dim3(256), 0, stream,
                     node_ids, Tb, be, WgT, att_src, att_dst, xb, h, a_s, a_d);
  hipLaunchKernelGGL(k_att, dim3(BGRAPH), dim3(512), 0, stream,
                     src, dst, h, a_s, a_d, bg, ab);
  hipLaunchKernelGGL(k_gru, dim3(256), dim3(768), 0, stream, ab, xb, WT, bc);
  hipLaunchKernelGGL(k_h, dim3(NNODES / 128), dim3(256), 0, stream,
                     xb, WgT, att_src, att_dst, h, a_s, a_d);
  hipLaunchKernelGGL(k_att, dim3(BGRAPH), dim3(512), 0, stream,
                     src, dst, h, a_s, a_d, bg, ab);
  hipLaunchKernelGGL(k_gru, dim3(256), dim3(768), 0, stream, ab, xb, WT, bc);
  hipLaunchKernelGGL(k_readout, dim3(BGRAPH), dim3(256), 0, stream, xb, WembT, Wmlp, out);
}

// Round 12
// 234.070 us; speedup vs baseline: 2.0293x; 1.0869x over previous
//
#include <hip/hip_runtime.h>
#include <hip/hip_bf16.h>

#define NNODES 131072
#define LGRAPH 256
#define BGRAPH 512
#define DIN 300
#define DH 96
#define EPG 2048
#define VOCAB 50001
#define NCLS 20
#define NEG 0.2f
#define EMB_ROWS 50048   // VOCAB padded to 128-row tiles
#define EMB_K 320        // 300 padded to 32-multiple
#define WS 100           // padded LDS stride (halfs), conflict-free for b128
#define XS 104           // padded LDS stride (halfs) for x/h tiles

typedef __attribute__((ext_vector_type(4))) float f32x4;
typedef __attribute__((ext_vector_type(8))) short bf16x8;
typedef __attribute__((ext_vector_type(8))) unsigned short u16x8;
#define MFMA16(a, b, c) __builtin_amdgcn_mfma_f32_16x16x32_bf16(a, b, c, 0, 0, 0)

__device__ __forceinline__ unsigned short f2b(float f) {
  __hip_bfloat16 h = __float2bfloat16(f);
  return *reinterpret_cast<unsigned short*>(&h);
}
__device__ __forceinline__ float b2f(unsigned short u) {
  unsigned v = ((unsigned)u) << 16;
  return __uint_as_float(v);
}
__device__ __forceinline__ float sigm(float v) { return 1.f / (1.f + __expf(-v)); }
// tanh(x) = 2*sigmoid(2x) - 1 : overflow-safe both directions, ~5 VALU ops
__device__ __forceinline__ float ftanh(float x) {
  return 2.f / (1.f + __expf(-2.f * x)) - 1.f;
}

// ---- weight prep: W[k][c] f32 -> WT[c][k] bf16 ; WeT ; combined biases ----
__global__ void k_prep_w(const float* __restrict__ Wg, const float* __restrict__ Wz0,
                         const float* __restrict__ Wz1, const float* __restrict__ Wr0,
                         const float* __restrict__ Wr1, const float* __restrict__ Wh0,
                         const float* __restrict__ Wh1, const float* __restrict__ Wemb,
                         const float* __restrict__ We,
                         const float* __restrict__ bz0, const float* __restrict__ bz1,
                         const float* __restrict__ br0, const float* __restrict__ br1,
                         const float* __restrict__ bh0, const float* __restrict__ bh1,
                         unsigned short* __restrict__ WT, unsigned short* __restrict__ WeT,
                         float* __restrict__ bc) {
  const int b = blockIdx.x, t = threadIdx.x;
  if (b < 8) {
    const float* src = (b == 0) ? Wg : (b == 1) ? Wz0 : (b == 2) ? Wz1 : (b == 3) ? Wr0
                     : (b == 4) ? Wr1 : (b == 5) ? Wh0 : (b == 6) ? Wh1 : Wemb;
    unsigned short* dst = WT + b * DH * DH;
    for (int i = t; i < DH * DH; i += 256) {
      int c = i / DH, k = i - c * DH;
      dst[i] = f2b(src[k * DH + c]);
    }
  } else if (b == 8) {
    for (int i = t; i < DH * EMB_K; i += 256) {
      int c = i / EMB_K, k = i - c * EMB_K;
      WeT[i] = (k < DIN) ? f2b(We[k * DH + c]) : (unsigned short)0;
    }
  } else {
    if (t < DH) {
      bc[t] = bz0[t] + bz1[t];
      bc[DH + t] = br0[t] + br1[t];
      bc[2 * DH + t] = bh0[t] + bh1[t];
    }
  }
}

// ---- Tb = embed @ We  (MFMA, M-tile 128, f32 A converted in-reg, bf16 out) ----
__device__ __forceinline__ bf16x8 ldcvt(const float* __restrict__ p, int row, int ko) {
  bf16x8 r;
  if (row < VOCAB) {
    float4 c0 = (ko + 4 <= DIN) ? *(const float4*)&p[row * DIN + ko]
                                : make_float4(0.f, 0.f, 0.f, 0.f);
    float4 c1 = (ko + 8 <= DIN) ? *(const float4*)&p[row * DIN + ko + 4]
                                : make_float4(0.f, 0.f, 0.f, 0.f);
    r[0] = (short)f2b(c0.x); r[1] = (short)f2b(c0.y);
    r[2] = (short)f2b(c0.z); r[3] = (short)f2b(c0.w);
    r[4] = (short)f2b(c1.x); r[5] = (short)f2b(c1.y);
    r[6] = (short)f2b(c1.z); r[7] = (short)f2b(c1.w);
  } else {
    #pragma unroll
    for (int j = 0; j < 8; ++j) r[j] = 0;
  }
  return r;
}

__global__ void k_emb_mm(const float* __restrict__ embed,
                         const unsigned short* __restrict__ WeT,
                         unsigned short* __restrict__ Tb) {
  const int t = threadIdx.x, w = t >> 6, l = t & 63, li = l & 15, lh = l >> 4;
  const int wbase = blockIdx.x * 128 + w * 32;
  f32x4 acc[2][6];
  #pragma unroll
  for (int rt = 0; rt < 2; rt++)
    #pragma unroll
    for (int ct = 0; ct < 6; ct++) acc[rt][ct] = (f32x4)0.f;
  for (int ks = 0; ks < 10; ++ks) {
    const int ko = lh * 8 + ks * 32;
    bf16x8 aA0 = ldcvt(embed, wbase + li, ko);
    bf16x8 aA1 = ldcvt(embed, wbase + 16 + li, ko);
    #pragma unroll
    for (int ct = 0; ct < 6; ct++) {
      bf16x8 bB = *(const bf16x8*)&WeT[(ct * 16 + li) * EMB_K + ko];
      acc[0][ct] = MFMA16(aA0, bB, acc[0][ct]);
      acc[1][ct] = MFMA16(aA1, bB, acc[1][ct]);
    }
  }
  #pragma unroll
  for (int rt = 0; rt < 2; rt++)
    #pragma unroll
    for (int ct = 0; ct < 6; ct++)
      #pragma unroll
      for (int r = 0; r < 4; r++)
        Tb[(wbase + rt * 16 + lh * 4 + r) * DH + ct * 16 + li] = f2b(acc[rt][ct][r]);
}

// ---- fused gather + tanh + h/a_s/a_d (step 0); 256 thr, 128 nodes/block ----
__global__ __launch_bounds__(256) void k_gh(
    const int* __restrict__ ids, const unsigned short* __restrict__ Tb,
    const float* __restrict__ be, const unsigned short* __restrict__ WgT,
    const float* __restrict__ att_s, const float* __restrict__ att_d,
    unsigned short* __restrict__ xb, unsigned short* __restrict__ h,
    float* __restrict__ a_s, float* __restrict__ a_d) {
  __shared__ __align__(16) unsigned short sX[128 * XS];   // 26624 B
  __shared__ int s_id[128];
  __shared__ float s_be[DH];
  const int t = threadIdx.x, w = t >> 6, l = t & 63, li = l & 15, lh = l >> 4;
  const int nb0 = blockIdx.x * 128;
  bf16x8 WF[6][3];
  #pragma unroll
  for (int ct = 0; ct < 6; ++ct)
    #pragma unroll
    for (int ks = 0; ks < 3; ++ks)
      WF[ct][ks] = *(const bf16x8*)&WgT[(ct * 16 + li) * DH + lh * 8 + ks * 32];
  if (t < 128) s_id[t] = ids[nb0 + t];
  if (t < DH) s_be[t] = be[t];
  __syncthreads();
  #pragma unroll
  for (int j = 0; j < 6; ++j) {
    int idx = t + 256 * j;                 // 1536 = 128 rows x 12 chunks
    int row = idx / 12, ch = idx - row * 12;
    u16x8 v = *(const u16x8*)&Tb[s_id[row] * DH + ch * 8];
    u16x8 o;
    #pragma unroll
    for (int k = 0; k < 8; ++k) o[k] = f2b(ftanh(b2f(v[k]) + s_be[ch * 8 + k]));
    *(u16x8*)&sX[row * XS + ch * 8] = o;
    *(u16x8*)&xb[(nb0 + row) * DH + ch * 8] = o;
  }
  __syncthreads();
  const int wbase = w * 32;
  f32x4 acc[2][6];
  #pragma unroll
  for (int rt = 0; rt < 2; rt++)
    #pragma unroll
    for (int ct = 0; ct < 6; ct++) acc[rt][ct] = (f32x4)0.f;
  bf16x8 aA[2][3];
  #pragma unroll
  for (int rt = 0; rt < 2; rt++)
    #pragma unroll
    for (int ks = 0; ks < 3; ks++)
      aA[rt][ks] = *(const bf16x8*)&sX[(wbase + rt * 16 + li) * XS + lh * 8 + ks * 32];
  #pragma unroll
  for (int ks = 0; ks < 3; ++ks)
    #pragma unroll
    for (int ct = 0; ct < 6; ct++) {
      acc[0][ct] = MFMA16(aA[0][ks], WF[ct][ks], acc[0][ct]);
      acc[1][ct] = MFMA16(aA[1][ks], WF[ct][ks], acc[1][ct]);
    }
  float ps[2][4] = {}, pd[2][4] = {};
  #pragma unroll
  for (int rt = 0; rt < 2; rt++)
    #pragma unroll
    for (int ct = 0; ct < 6; ct++) {
      const int col = ct * 16 + li;
      const float as_ = att_s[col], ad_ = att_d[col];
      #pragma unroll
      for (int r = 0; r < 4; r++) {
        float v = acc[rt][ct][r];
        h[(nb0 + wbase + rt * 16 + lh * 4 + r) * DH + col] = f2b(v);
        ps[rt][r] += v * as_;
        pd[rt][r] += v * ad_;
      }
    }
  #pragma unroll
  for (int rt = 0; rt < 2; rt++)
    #pragma unroll
    for (int r = 0; r < 4; r++) {
      float s = ps[rt][r], d = pd[rt][r];
      #pragma unroll
      for (int m = 1; m < 16; m <<= 1) { s += __shfl_xor(s, m); d += __shfl_xor(d, m); }
      if (li == 0) {
        const int row = nb0 + wbase + rt * 16 + lh * 4 + r;
        a_s[row] = s;
        a_d[row] = d;
      }
    }
}

// ---- h = xb @ Wg (bf16 out) + a_s/a_d reductions (step 1; MFMA, W in LDS) ----
__global__ __launch_bounds__(256) void k_h(
    const unsigned short* __restrict__ xb, const unsigned short* __restrict__ WgT,
    const float* __restrict__ att_s, const float* __restrict__ att_d,
    unsigned short* __restrict__ h, float* __restrict__ a_s,
    float* __restrict__ a_d) {
  __shared__ __align__(16) unsigned short sW[DH * WS];   // 19200 B
  const int t = threadIdx.x, w = t >> 6, l = t & 63, li = l & 15, lh = l >> 4;
  const int wbase = blockIdx.x * 128 + w * 32;
  for (int i = t; i < DH * 12; i += 256) {
    int r = i / 12, c8 = i - r * 12;
    *(int4*)&sW[r * WS + c8 * 8] = *(const int4*)&WgT[r * DH + c8 * 8];
  }
  __syncthreads();
  f32x4 acc[2][6];
  #pragma unroll
  for (int rt = 0; rt < 2; rt++)
    #pragma unroll
    for (int ct = 0; ct < 6; ct++) acc[rt][ct] = (f32x4)0.f;
  #pragma unroll
  for (int ks = 0; ks < 3; ++ks) {
    const int ko = lh * 8 + ks * 32;
    bf16x8 aA0 = *(const bf16x8*)&xb[(wbase + li) * DH + ko];
    bf16x8 aA1 = *(const bf16x8*)&xb[(wbase + 16 + li) * DH + ko];
    #pragma unroll
    for (int ct = 0; ct < 6; ct++) {
      bf16x8 bB = *(const bf16x8*)&sW[(ct * 16 + li) * WS + ko];
      acc[0][ct] = MFMA16(aA0, bB, acc[0][ct]);
      acc[1][ct] = MFMA16(aA1, bB, acc[1][ct]);
    }
  }
  float ps[2][4] = {}, pd[2][4] = {};
  #pragma unroll
  for (int rt = 0; rt < 2; rt++)
    #pragma unroll
    for (int ct = 0; ct < 6; ct++) {
      const int col = ct * 16 + li;
      const float as_ = att_s[col], ad_ = att_d[col];
      #pragma unroll
      for (int r = 0; r < 4; r++) {
        float v = acc[rt][ct][r];
        h[(wbase + rt * 16 + lh * 4 + r) * DH + col] = f2b(v);
        ps[rt][r] += v * as_;
        pd[rt][r] += v * ad_;
      }
    }
  #pragma unroll
  for (int rt = 0; rt < 2; rt++)
    #pragma unroll
    for (int r = 0; r < 4; r++) {
      float s = ps[rt][r], d = pd[rt][r];
      #pragma unroll
      for (int m = 1; m < 16; m <<= 1) { s += __shfl_xor(s, m); d += __shfl_xor(d, m); }
      if (li == 0) {
        const int row = wbase + rt * 16 + lh * 4 + r;
        a_s[row] = s;
        a_d[row] = d;
      }
    }
}

// ---- per-graph GAT via CSR gather; 512 thr, 2 threads/node (48 cols each) ----
__global__ __launch_bounds__(512, 4) void k_att(
    const int* __restrict__ src, const int* __restrict__ dst,
    const unsigned short* __restrict__ h, const float* __restrict__ a_sg,
    const float* __restrict__ a_dg, const float* __restrict__ bg,
    unsigned short* __restrict__ aout) {
  __shared__ __align__(16) unsigned short sH[LGRAPH * XS];  // 53248 B
  __shared__ float s_ev[EPG];
  __shared__ unsigned char s_sl[EPG], s_dl[EPG];
  __shared__ unsigned char s_srcS[EPG];
  __shared__ int s_cnt[LGRAPH], s_off[LGRAPH], s_pos[LGRAPH];
  __shared__ float s_as[LGRAPH], s_ad[LGRAPH];
  __shared__ float s_bg[DH];
  const int g = blockIdx.x, t = threadIdx.x;
  const int nb = g * LGRAPH;
  if (t < LGRAPH) { s_cnt[t] = 0; s_as[t] = a_sg[nb + t]; s_ad[t] = a_dg[nb + t]; }
  if (t < DH) s_bg[t] = bg[t];
  #pragma unroll
  for (int j = 0; j < 6; ++j) {
    int idx = t + 512 * j;
    int row = idx / 12, ch = idx - row * 12;
    *(int4*)&sH[row * XS + ch * 8] = *(const int4*)&h[(nb + row) * DH + ch * 8];
  }
  __syncthreads();
  for (int e = t; e < EPG; e += 512) {
    int sl = src[g * EPG + e] - nb, dl = dst[g * EPG + e] - nb;
    s_sl[e] = (unsigned char)sl;
    s_dl[e] = (unsigned char)dl;
    atomicAdd(&s_cnt[dl], 1);
  }
  __syncthreads();
  if (t < 64) {
    int carry = 0;
    #pragma unroll
    for (int c = 0; c < 4; ++c) {
      int v = s_cnt[c * 64 + t];
      int x = v;
      #pragma unroll
      for (int o = 1; o < 64; o <<= 1) {
        int y = __shfl_up(x, o);
        if (t >= o) x += y;
      }
      s_off[c * 64 + t] = x - v + carry;
      carry += __shfl(x, 63);
    }
  }
  __syncthreads();
  if (t < LGRAPH) s_pos[t] = s_off[t];
  __syncthreads();
  for (int e = t; e < EPG; e += 512) {
    int sl = s_sl[e], dl = s_dl[e];
    float ee = s_as[sl] + s_ad[dl];
    ee = ee > 0.f ? ee : NEG * ee;
    int pos = atomicAdd(&s_pos[dl], 1);
    s_srcS[pos] = (unsigned char)sl;
    s_ev[pos] = ee;
  }
  __syncthreads();
  {
    const int d = t >> 1, half = t & 1;
    const int beg = s_off[d], end = beg + s_cnt[d];
    float ss = s_as[d] + s_ad[d];
    ss = ss > 0.f ? ss : NEG * ss;
    float m = ss;
    for (int i = beg; i < end; ++i) m = fmaxf(m, s_ev[i]);
    const int cbase = half * 48;
    float acc[48];
    float wself = __expf(ss - m);
    float den = wself;
    #pragma unroll
    for (int k = 0; k < 6; ++k) {
      u16x8 v = *(const u16x8*)&sH[d * XS + cbase + k * 8];
      #pragma unroll
      for (int j = 0; j < 8; ++j) acc[k * 8 + j] = wself * b2f(v[j]);
    }
    for (int i = beg; i < end; ++i) {
      float wv = __expf(s_ev[i] - m);
      den += wv;
      int sl2 = s_srcS[i];
      #pragma unroll
      for (int k = 0; k < 6; ++k) {
        u16x8 v = *(const u16x8*)&sH[sl2 * XS + cbase + k * 8];
        #pragma unroll
        for (int j = 0; j < 8; ++j) acc[k * 8 + j] += wv * b2f(v[j]);
      }
    }
    float inv = 1.f / den;
    unsigned short* op = &aout[(nb + d) * DH + cbase];
    #pragma unroll
    for (int k = 0; k < 6; ++k) {
      u16x8 o;
      #pragma unroll
      for (int j = 0; j < 8; ++j) o[j] = f2b(acc[k * 8 + j] * inv + s_bg[cbase + k * 8 + j]);
      *(u16x8*)&op[k * 8] = o;
    }
  }
}

// ---- fused GRU, persistent blocks, weights in LDS, 12 waves (4 rows x 3 cols) ----
// 256 blocks x 768 thr; wave wr=w/3 rows wr*32..+32, wc=w%3 cols wc*32..+32.
__global__ __launch_bounds__(768, 3) void k_gru(
    const unsigned short* __restrict__ ab, unsigned short* __restrict__ xb,
    const unsigned short* __restrict__ WT, const float* __restrict__ bc) {
  __shared__ __align__(16) unsigned short sW[6 * DH * WS];   // 115200 B
  __shared__ __align__(16) unsigned short sX[128 * WS];      // 25600 B
  const int t = threadIdx.x, w = t >> 6, l = t & 63, li = l & 15, lh = l >> 4;
  const int wr = w / 3, wc = w - wr * 3;
  // stage weights: order Wr0,Wr1,Wz0,Wz1,Wh0,Wh1 (WT idx 3,4,1,2,5,6)
  #pragma unroll
  for (int m = 0; m < 6; ++m) {
    const int srcm = (m == 0) ? 3 : (m == 1) ? 4 : (m == 2) ? 1 : (m == 3) ? 2 : (m == 4) ? 5 : 6;
    const unsigned short* srcp = WT + srcm * DH * DH;
    for (int i = t; i < DH * 12; i += 768) {
      int r = i / 12, c8 = i - r * 12;
      *(int4*)&sW[(m * DH + r) * WS + c8 * 8] = *(const int4*)&srcp[r * DH + c8 * 8];
    }
  }
  float zb_[2], rb_[2], hb_[2];
  #pragma unroll
  for (int ct = 0; ct < 2; ++ct) {
    const int col = wc * 32 + ct * 16 + li;
    zb_[ct] = bc[col]; rb_[ct] = bc[DH + col]; hb_[ct] = bc[2 * DH + col];
  }

  for (int tile = 0; tile < 4; ++tile) {
    const int nb0 = (blockIdx.x * 4 + tile) * 128;
    __syncthreads();   // sX free
    #pragma unroll
    for (int j = 0; j < 2; ++j) {
      int idx = t + 768 * j;
      int row = idx / 12, ch = idx - row * 12;
      *(int4*)&sX[row * WS + ch * 8] = *(const int4*)&xb[(nb0 + row) * DH + ch * 8];
    }
    __syncthreads();
    bf16x8 aA[2][3], aX[2][3];
    #pragma unroll
    for (int rt = 0; rt < 2; rt++)
      #pragma unroll
      for (int ks = 0; ks < 3; ks++) {
        const int row = wr * 32 + rt * 16 + li;
        const int ko = lh * 8 + ks * 32;
        aA[rt][ks] = *(const bf16x8*)&ab[(nb0 + row) * DH + ko];
        aX[rt][ks] = *(const bf16x8*)&sX[row * WS + ko];
      }
    float xo[2][2][4];
    #pragma unroll
    for (int rt = 0; rt < 2; rt++)
      #pragma unroll
      for (int ct = 0; ct < 2; ct++)
        #pragma unroll
        for (int r = 0; r < 4; r++)
          xo[rt][ct][r] = b2f(sX[(wr * 32 + rt * 16 + lh * 4 + r) * WS + wc * 32 + ct * 16 + li]);
    f32x4 accR[2][2], accZ[2][2];
    #pragma unroll
    for (int rt = 0; rt < 2; rt++)
      #pragma unroll
      for (int ct = 0; ct < 2; ct++) { accR[rt][ct] = (f32x4)0.f; accZ[rt][ct] = (f32x4)0.f; }
    #pragma unroll
    for (int ks = 0; ks < 3; ks++) {
      const int ko = lh * 8 + ks * 32;
      #pragma unroll
      for (int ct = 0; ct < 2; ct++) {
        const int wrow = wc * 32 + ct * 16 + li;
        bf16x8 w_r0 = *(const bf16x8*)&sW[(0 * DH + wrow) * WS + ko];
        bf16x8 w_r1 = *(const bf16x8*)&sW[(1 * DH + wrow) * WS + ko];
        bf16x8 w_z0 = *(const bf16x8*)&sW[(2 * DH + wrow) * WS + ko];
        bf16x8 w_z1 = *(const bf16x8*)&sW[(3 * DH + wrow) * WS + ko];
        #pragma unroll
        for (int rt = 0; rt < 2; rt++) {
          accR[rt][ct] = MFMA16(aA[rt][ks], w_r0, accR[rt][ct]);
          accR[rt][ct] = MFMA16(aX[rt][ks], w_r1, accR[rt][ct]);
          accZ[rt][ct] = MFMA16(aA[rt][ks], w_z0, accZ[rt][ct]);
          accZ[rt][ct] = MFMA16(aX[rt][ks], w_z1, accZ[rt][ct]);
        }
      }
    }
    __syncthreads();   // all sX reads done
    #pragma unroll
    for (int rt = 0; rt < 2; rt++)
      #pragma unroll
      for (int ct = 0; ct < 2; ct++) {
        const int col = wc * 32 + ct * 16 + li;
        #pragma unroll
        for (int r = 0; r < 4; r++) {
          float rv = sigm(accR[rt][ct][r] + rb_[ct]);
          sX[(wr * 32 + rt * 16 + lh * 4 + r) * WS + col] = f2b(xo[rt][ct][r] * rv);
        }
      }
    __syncthreads();   // u visible
    bf16x8 aU[2][3];
    #pragma unroll
    for (int rt = 0; rt < 2; rt++)
      #pragma unroll
      for (int ks = 0; ks < 3; ks++)
        aU[rt][ks] = *(const bf16x8*)&sX[(wr * 32 + rt * 16 + li) * WS + lh * 8 + ks * 32];
    __syncthreads();   // aU reads done before xn overwrite
    f32x4 accH[2][2];
    #pragma unroll
    for (int rt = 0; rt < 2; rt++)
      #pragma unroll
      for (int ct = 0; ct < 2; ct++) accH[rt][ct] = (f32x4)0.f;
    #pragma unroll
    for (int ks = 0; ks < 3; ks++) {
      const int ko = lh * 8 + ks * 32;
      #pragma unroll
      for (int ct = 0; ct < 2; ct++) {
        const int wrow = wc * 32 + ct * 16 + li;
        bf16x8 w_h0 = *(const bf16x8*)&sW[(4 * DH + wrow) * WS + ko];
        bf16x8 w_h1 = *(const bf16x8*)&sW[(5 * DH + wrow) * WS + ko];
        #pragma unroll
        for (int rt = 0; rt < 2; rt++) {
          accH[rt][ct] = MFMA16(aA[rt][ks], w_h0, accH[rt][ct]);
          accH[rt][ct] = MFMA16(aU[rt][ks], w_h1, accH[rt][ct]);
        }
      }
    }
    #pragma unroll
    for (int rt = 0; rt < 2; rt++)
      #pragma unroll
      for (int ct = 0; ct < 2; ct++) {
        const int col = wc * 32 + ct * 16 + li;
        #pragma unroll
        for (int r = 0; r < 4; r++) {
          float z = sigm(accZ[rt][ct][r] + zb_[ct]);
          float hh = ftanh(accH[rt][ct][r] + hb_[ct]);
          float xn = hh * z + xo[rt][ct][r] * (1.f - z);
          sX[(wr * 32 + rt * 16 + lh * 4 + r) * WS + col] = f2b(xn);
        }
      }
    __syncthreads();
    #pragma unroll
    for (int j = 0; j < 2; ++j) {
      int idx = t + 768 * j;
      int row = idx / 12, ch = idx - row * 12;
      *(int4*)&xb[(nb0 + row) * DH + ch * 8] = *(const int4*)&sX[row * WS + ch * 8];
    }
  }
}

// ---- readout: y = tanh(xb @ Wemb); pool max+mean; out = pooled @ Wmlp ----
__global__ __launch_bounds__(256) void k_readout(
    const unsigned short* __restrict__ xb, const unsigned short* __restrict__ WembT,
    const float* __restrict__ Wmlp, float* __restrict__ out) {
  __shared__ __align__(16) unsigned short sW[DH * WS];   // 19200 B
  __shared__ float pmaxs[4][DH], psums[4][DH];
  __shared__ float spool[DH];
  const int g = blockIdx.x, t = threadIdx.x, w = t >> 6, l = t & 63, li = l & 15, lh = l >> 4;
  const int wbase = g * LGRAPH + w * 64;
  for (int i = t; i < DH * 12; i += 256) {
    int r = i / 12, c8 = i - r * 12;
    *(int4*)&sW[r * WS + c8 * 8] = *(const int4*)&WembT[r * DH + c8 * 8];
  }
  __syncthreads();
  f32x4 acc[4][6];
  #pragma unroll
  for (int rt = 0; rt < 4; rt++)
    #pragma unroll
    for (int ct = 0; ct < 6; ct++) acc[rt][ct] = (f32x4)0.f;
  #pragma unroll
  for (int ks = 0; ks < 3; ks++) {
    const int ko = lh * 8 + ks * 32;
    bf16x8 aA[4];
    #pragma unroll
    for (int rt = 0; rt < 4; rt++)
      aA[rt] = *(const bf16x8*)&xb[(wbase + rt * 16 + li) * DH + ko];
    #pragma unroll
    for (int ct = 0; ct < 6; ct++) {
      bf16x8 bB = *(const bf16x8*)&sW[(ct * 16 + li) * WS + ko];
      #pragma unroll
      for (int rt = 0; rt < 4; rt++) acc[rt][ct] = MFMA16(aA[rt], bB, acc[rt][ct]);
    }
  }
  float pm[6], psu[6];
  #pragma unroll
  for (int ct = 0; ct < 6; ct++) {
    float mx = -1e30f, sm = 0.f;
    #pragma unroll
    for (int rt = 0; rt < 4; rt++)
      #pragma unroll
      for (int r = 0; r < 4; r++) {
        float y = ftanh(acc[rt][ct][r]);
        mx = fmaxf(mx, y);
        sm += y;
      }
    pm[ct] = mx; psu[ct] = sm;
  }
  #pragma unroll
  for (int ct = 0; ct < 6; ct++) {
    pm[ct] = fmaxf(pm[ct], __shfl_xor(pm[ct], 16));
    psu[ct] += __shfl_xor(psu[ct], 16);
    pm[ct] = fmaxf(pm[ct], __shfl_xor(pm[ct], 32));
    psu[ct] += __shfl_xor(psu[ct], 32);
  }
  if (lh == 0) {
    #pragma unroll
    for (int ct = 0; ct < 6; ct++) {
      pmaxs[w][ct * 16 + li] = pm[ct];
      psums[w][ct * 16 + li] = psu[ct];
    }
  }
  __syncthreads();
  if (t < DH) {
    float mx = fmaxf(fmaxf(pmaxs[0][t], pmaxs[1][t]), fmaxf(pmaxs[2][t], pmaxs[3][t]));
    float sm = psums[0][t] + psums[1][t] + psums[2][t] + psums[3][t];
    spool[t] = mx + sm * (1.f / LGRAPH);
  }
  __syncthreads();
  if (t < NCLS) {
    float a = 0.f;
    for (int k = 0; k < DH; ++k) a += spool[k] * Wmlp[k * NCLS + t];
    out[g * NCLS + t] = a;
  }
}

extern "C" void kernel_launch(void* const* d_in, const int* in_sizes, int n_in,
                              void* d_out, int out_size, void* d_ws, size_t ws_size,
                              hipStream_t stream) {
  const int*   node_ids = (const int*)d_in[0];
  const int*   src      = (const int*)d_in[1];
  const int*   dst      = (const int*)d_in[2];
  const float* embed    = (const float*)d_in[3];
  const float* We   = (const float*)d_in[4];
  const float* be   = (const float*)d_in[5];
  const float* Wg   = (const float*)d_in[6];
  const float* att_src = (const float*)d_in[7];
  const float* att_dst = (const float*)d_in[8];
  const float* bg   = (const float*)d_in[9];
  const float* Wz0  = (const float*)d_in[10];
  const float* bz0  = (const float*)d_in[11];
  const float* Wz1  = (const float*)d_in[12];
  const float* bz1  = (const float*)d_in[13];
  const float* Wr0  = (const float*)d_in[14];
  const float* br0  = (const float*)d_in[15];
  const float* Wr1  = (const float*)d_in[16];
  const float* br1  = (const float*)d_in[17];
  const float* Wh0  = (const float*)d_in[18];
  const float* bh0  = (const float*)d_in[19];
  const float* Wh1  = (const float*)d_in[20];
  const float* bh1  = (const float*)d_in[21];
  const float* Wemb = (const float*)d_in[22];
  const float* Wmlp = (const float*)d_in[23];
  float* out = (float*)d_out;

  char* w_ = (char*)d_ws;
  unsigned short* xb   = (unsigned short*)(w_ + 0);           // 25,165,824 B
  unsigned short* ab   = (unsigned short*)(w_ + 25165824);    // 25,165,824 B
  unsigned short* h    = (unsigned short*)(w_ + 50331648);    // 25,165,824 B
  unsigned short* Tb   = (unsigned short*)(w_ + 75497472);    // 9,609,216 B
  float*          a_s  = (float*)(w_ + 85106688);             // 524,288 B
  float*          a_d  = (float*)(w_ + 85630976);             // 524,288 B
  unsigned short* WT   = (unsigned short*)(w_ + 86155264);    // 147,456 B
  unsigned short* WeT  = (unsigned short*)(w_ + 86302720);    // 61,440 B
  float*          bc   = (float*)(w_ + 86364160);             // 1,152 B

  unsigned short* WgT   = WT + 0 * DH * DH;
  unsigned short* WembT = WT + 7 * DH * DH;

  hipLaunchKernelGGL(k_prep_w, dim3(10), dim3(256), 0, stream,
                     Wg, Wz0, Wz1, Wr0, Wr1, Wh0, Wh1, Wemb, We,
                     bz0, bz1, br0, br1, bh0, bh1, WT, WeT, bc);
  hipLaunchKernelGGL(k_emb_mm, dim3(EMB_ROWS / 128), dim3(256), 0, stream, embed, WeT, Tb);
  hipLaunchKernelGGL(k_gh, dim3(NNODES / 128), dim3(256), 0, stream,
                     node_ids, Tb, be, WgT, att_src, att_dst, xb, h, a_s, a_d);
  hipLaunchKernelGGL(k_att, dim3(BGRAPH), dim3(512), 0, stream,
                     src, dst, h, a_s, a_d, bg, ab);
  hipLaunchKernelGGL(k_gru, dim3(256), dim3(768), 0, stream, ab, xb, WT, bc);
  hipLaunchKernelGGL(k_h, dim3(NNODES / 128), dim3(256), 0, stream,
                     xb, WgT, att_src, att_dst, h, a_s, a_d);
  hipLaunchKernelGGL(k_att, dim3(BGRAPH), dim3(512), 0, stream,
                     src, dst, h, a_s, a_d, bg, ab);
  hipLaunchKernelGGL(k_gru, dim3(256), dim3(768), 0, stream, ab, xb, WT, bc);
  hipLaunchKernelGGL(k_readout, dim3(BGRAPH), dim3(256), 0, stream, xb, WembT, Wmlp, out);
}